// Round 11
// baseline (200.651 us; speedup 1.0000x reference)
//
#include <hip/hip_runtime.h>
#include <hip/hip_bf16.h>

// GDGCN: out[b,c,m,t] = sum_n softmax_row(relu(t1 nv2^T))[n,m] * x[b,c,n,t]
// t1 = nv1 @ (sum_d tv[d] k[d,:,:]);  N=8192, D=32, cols = B*C*T = 192.
// R22: pipeline restructure, 5 kernels -> 4. The R21 data showed per-
// kernel compute is ~97us of a 172us total: the rest is launch gaps /
// drain boundaries / tiny low-occupancy kernels. Changes:
//  1) softmax 1/sums folded into k_mega's E-gen (rinv LDS table built per
//     block from per-chunk partials) -> k_y no longer needs sums.
//  2) k_prep + k_y fused into k_pre (512 blocks: cs redundant + 16 t1
//     rows + 512 nv2b + 256x12 x-transpose each). One launch removed.
//  3) k_stats atomic-free: writes sums_part[chunk][n]; no zero-init, no
//     atomics, deterministic j-order sum in k_mega prologue.
// k_mega core structure unchanged (proven): col-split waves, LDS-E dbuf,
// RAWBAR (lgkmcnt-only), ESTR 70, setprio, bf16 part.
// E-pack: bit-exact RNE f2bf only (v_cvt_pk_bf16_f32 NOT RNE, R14).

#define NN 8192
#define DD 32
#define TT 12
#define NSPLIT 8
#define CHUNK 1024
#define ESTR 70  // LDS row stride (ushort)

typedef __attribute__((ext_vector_type(8))) short bf16x8;
typedef __attribute__((ext_vector_type(4))) short bf16x4;
typedef __attribute__((ext_vector_type(4))) float f32x4;

static __device__ __forceinline__ unsigned short f2bf(float f) {
  unsigned int u = __float_as_uint(f);
  u = (u + 0x7FFFu + ((u >> 16) & 1u)) >> 16;  // RNE bf16
  return (unsigned short)u;
}

static __device__ __forceinline__ float fexp2(float x) {
#if __has_builtin(__builtin_amdgcn_exp2f)
  return __builtin_amdgcn_exp2f(x);
#else
  return __builtin_exp2f(x);
#endif
}

// Raw barrier: LDS-visibility only (lgkmcnt). Global loads stay in flight.
#define RAWBAR()                                          \
  do {                                                    \
    asm volatile("s_waitcnt lgkmcnt(0)" ::: "memory");    \
    __builtin_amdgcn_sched_barrier(0);                    \
    __builtin_amdgcn_s_barrier();                         \
  } while (0)

// ---- k_pre: core = tv.k ; t1 rows ; nv2 -> bf16 ; yT = bf16(x) transpose ----
// 512 blocks: block b = (bc = b>>5, xb = b&31).
//   t1 rows [b*16, +16); nv2b [b*512, +512); yT for (bc, n0 = xb*256).
__global__ __launch_bounds__(256) void k_pre(const float* __restrict__ x,
                                             const float* __restrict__ nv1,
                                             const float* __restrict__ nv2,
                                             const float* __restrict__ timevec,
                                             const float* __restrict__ kk,
                                             const int* __restrict__ tind,
                                             unsigned short* __restrict__ t1b,
                                             unsigned short* __restrict__ nv2b,
                                             unsigned short* __restrict__ yT) {
  __shared__ float cs[1024];
  __shared__ float xs[3328];  // 256 * 13 (pad kills stride-12 conflicts)
  const int tid = threadIdx.x;
  const int bid = blockIdx.x;
  const int bc = bid >> 5, xb = bid & 31;
  const int n0 = xb * 256;

  // phase 1: core (redundant per block, 32K FMA) + x chunk into LDS
  const float* tv = timevec + (size_t)tind[0] * DD;
  for (int idx = tid; idx < 1024; idx += 256) {
    float acc = 0.f;
#pragma unroll
    for (int d = 0; d < DD; ++d) acc += tv[d] * kk[d * 1024 + idx];
    cs[idx] = acc;
  }
  const float* xp = x + (size_t)bc * NN * TT + (size_t)n0 * TT;
#pragma unroll
  for (int j = 0; j < 12; ++j) {
    const int idx = j * 256 + tid;
    xs[(idx / 12) * 13 + idx % 12] = xp[idx];
  }
  __syncthreads();

  // phase 2a: t1 rows [bid*16, +16) (f32 dots, bit-identical to old k_prep)
  const int f = tid & 31, sub = tid >> 5;
  const int tb = bid * 16;
#pragma unroll
  for (int it = 0; it < 2; ++it) {
    const int n = tb + it * 8 + sub;
    const float* nr = nv1 + (size_t)n * DD;
    float acc = 0.f;
#pragma unroll
    for (int e = 0; e < DD; ++e) acc += nr[e] * cs[e * DD + f];
    t1b[(size_t)n * DD + f] = f2bf(acc * 1.4426950408889634f);  // fold log2(e)
  }
  // phase 2b: nv2 -> bf16
#pragma unroll
  for (int it = 0; it < 2; ++it) {
    const int idx = bid * 512 + it * 256 + tid;
    nv2b[idx] = f2bf(nv2[idx]);
  }
  // phase 2c: yT[col][n] = bf16(x) (normalization moved into k_mega gen)
#pragma unroll
  for (int t = 0; t < 12; ++t)
    yT[(size_t)(bc * TT + t) * NN + n0 + tid] = f2bf(xs[tid * 13 + t]);
}

// ---- sums_part[j][n] = sum_{m in chunk j} exp2(relu(t1[n].nv2[m])) ----
// grid (128 n, 8 m-chunks of 1024); no atomics, no init, deterministic.
__global__ __launch_bounds__(256) void k_stats(const unsigned short* __restrict__ t1b,
                                               const unsigned short* __restrict__ nv2b,
                                               float* __restrict__ sumsp) {
  const int tid = threadIdx.x;
  const int w = tid >> 6, lane = tid & 63, q = lane >> 4, i16 = lane & 15;
  const int nbase = blockIdx.x * 64 + w * 16;
  bf16x8 a = *(const bf16x8*)(t1b + (size_t)(nbase + i16) * DD + q * 8);
  const f32x4 z4 = {0.f, 0.f, 0.f, 0.f};
  float s[4] = {0.f, 0.f, 0.f, 0.f};
  const int m0 = blockIdx.y * 1024;
#define LDB(mt, u) (*(const bf16x8*)(nv2b + (size_t)((mt) + (u)*16 + i16) * DD + q * 8))
  bf16x8 b0 = LDB(m0, 0), b1 = LDB(m0, 1), b2 = LDB(m0, 2), b3 = LDB(m0, 3);
  for (int mt = m0; mt < m0 + 1024; mt += 64) {
    const int mtn = (mt + 64 < m0 + 1024) ? (mt + 64) : mt;  // clamp: dummy reload
    bf16x8 n0 = LDB(mtn, 0), n1 = LDB(mtn, 1), n2 = LDB(mtn, 2), n3 = LDB(mtn, 3);
    f32x4 d;
    d = __builtin_amdgcn_mfma_f32_16x16x32_bf16(a, b0, z4, 0, 0, 0);
#pragma unroll
    for (int r = 0; r < 4; ++r) s[r] += fexp2(fmaxf(d[r], 0.f));
    d = __builtin_amdgcn_mfma_f32_16x16x32_bf16(a, b1, z4, 0, 0, 0);
#pragma unroll
    for (int r = 0; r < 4; ++r) s[r] += fexp2(fmaxf(d[r], 0.f));
    d = __builtin_amdgcn_mfma_f32_16x16x32_bf16(a, b2, z4, 0, 0, 0);
#pragma unroll
    for (int r = 0; r < 4; ++r) s[r] += fexp2(fmaxf(d[r], 0.f));
    d = __builtin_amdgcn_mfma_f32_16x16x32_bf16(a, b3, z4, 0, 0, 0);
#pragma unroll
    for (int r = 0; r < 4; ++r) s[r] += fexp2(fmaxf(d[r], 0.f));
    b0 = n0; b1 = n1; b2 = n2; b3 = n3;
  }
#undef LDB
#pragma unroll
  for (int r = 0; r < 4; ++r)
    for (int off = 1; off < 16; off <<= 1) s[r] += __shfl_xor(s[r], off, 64);
  if (i16 == 0) {
#pragma unroll
    for (int r = 0; r < 4; ++r)
      sumsp[(size_t)blockIdx.y * NN + nbase + q * 4 + r] = s[r];
  }
}

// ---- k_mega: part[nc][col][m] = sum_{n in chunk} E'[n][m] * y[col][n] ----
// E' = exp2(relu(.)) * rinv[n]  (softmax normalization applied E-side).
// grid (128 m-blocks of 64, 8 chunks of 1024 n); 256 thr = 4 waves.
// Prologue builds rinv LDS table (sum of 8 chunk partials, 1/s). Gen/acc
// structure proven: stage 64 n, dbuf Ew, RAWBAR, setprio, bf16 part.
__global__ __launch_bounds__(256, 4) void k_mega(const unsigned short* __restrict__ t1b,
                                                 const unsigned short* __restrict__ nv2b,
                                                 const unsigned short* __restrict__ yT,
                                                 const float* __restrict__ sumsp,
                                                 unsigned short* __restrict__ part) {
  const int tid = threadIdx.x;
  const int w = tid >> 6, lane = tid & 63, q = lane >> 4, i16 = lane & 15;
  const int mb = blockIdx.x * 64;
  const int nt0 = blockIdx.y * CHUNK;

  __shared__ unsigned short Ew[2][64][ESTR];  // 17920 B
  __shared__ f32x4 rinv_v[256];               //  4096 B: rinv[1024 n]

  // prologue A: rinv table (deterministic j-order sum, IEEE divide)
  {
    float* rl = (float*)rinv_v;
    for (int k = tid; k < 1024; k += 256) {
      float ssum = 0.f;
#pragma unroll
      for (int j = 0; j < NSPLIT; ++j) ssum += sumsp[(size_t)j * NN + nt0 + k];
      rl[k] = 1.0f / ssum;
    }
  }

  // gen B-frag (loop-invariant): B[d][m=i16] = nv2[mb + w*16 + i16][d]
  const bf16x8 bg = *(const bf16x8*)(nv2b + (size_t)(mb + w * 16 + i16) * DD + q * 8);
  const int rowm = w * 16 + i16;

  const f32x4 z4 = {0.f, 0.f, 0.f, 0.f};
  f32x4 acc[3][4];
#pragma unroll
  for (int c = 0; c < 3; ++c)
#pragma unroll
    for (int ms = 0; ms < 4; ++ms) acc[c][ms] = (f32x4){0.f, 0.f, 0.f, 0.f};

  RAWBAR();  // rinv table visible

  // prologue B: generate stage 0 (64 n) into buf 0, rinv applied
#pragma unroll
  for (int s = 0; s < 4; ++s) {
    bf16x8 at = *(const bf16x8*)(t1b + (size_t)(nt0 + s * 16 + i16) * DD + q * 8);
    f32x4 d = __builtin_amdgcn_mfma_f32_16x16x32_bf16(at, bg, z4, 0, 0, 0);
    const f32x4 rv = rinv_v[s * 4 + q];  // rinv[n = s*16 + q*4 + r]
    bf16x4 e;
#pragma unroll
    for (int r = 0; r < 4; ++r) e[r] = (short)f2bf(fexp2(fmaxf(d[r], 0.f)) * rv[r]);
    *(bf16x4*)&Ew[0][rowm][s * 16 + q * 4] = e;
  }
  RAWBAR();

  int p = 0;
  for (int st = 0; st < 16; ++st, p ^= 1) {
    const int nt = nt0 + st * 64;
    const bool more = (st < 15);

    // --- stage top: issue ALL global loads (y both halves, next t1) ---
    bf16x8 yfr0[3], yfr1[3];
#pragma unroll
    for (int c = 0; c < 3; ++c) {
      const unsigned short* ybase = yT + (size_t)((w * 3 + c) * 16 + i16) * NN + nt + q * 8;
      yfr0[c] = *(const bf16x8*)ybase;
      yfr1[c] = *(const bf16x8*)(ybase + 32);
    }
    bf16x8 atn[4];
    f32x4 rv[4];
    if (more) {
#pragma unroll
      for (int s = 0; s < 4; ++s) {
        atn[s] = *(const bf16x8*)(t1b + (size_t)(nt + 64 + s * 16 + i16) * DD + q * 8);
        rv[s] = rinv_v[(st + 1) * 16 + s * 4 + q];  // rinv for next-stage rows
      }
    }

    // half-0 E operands
    bf16x8 efr[4];
#pragma unroll
    for (int ms = 0; ms < 4; ++ms)
      efr[ms] = *(const bf16x8*)&Ew[p][ms * 16 + i16][q * 8];

    // gen first half (s0,s1) for stage st+1
    f32x4 d0, d1;
    if (more) {
      d0 = __builtin_amdgcn_mfma_f32_16x16x32_bf16(atn[0], bg, z4, 0, 0, 0);
      d1 = __builtin_amdgcn_mfma_f32_16x16x32_bf16(atn[1], bg, z4, 0, 0, 0);
    }

    // acc k-step 0 (12 MFMAs), priority-boosted (T5)
    __builtin_amdgcn_s_setprio(1);
#pragma unroll
    for (int c = 0; c < 3; ++c)
#pragma unroll
      for (int ms = 0; ms < 4; ++ms)
        acc[c][ms] = __builtin_amdgcn_mfma_f32_16x16x32_bf16(yfr0[c], efr[ms], acc[c][ms], 0, 0, 0);
    __builtin_amdgcn_s_setprio(0);

    // exp2*rinv + store s0,s1; gen + store s2,s3 (VALU overlaps MFMA)
    if (more) {
      bf16x4 e0, e1;
#pragma unroll
      for (int r = 0; r < 4; ++r) {
        e0[r] = (short)f2bf(fexp2(fmaxf(d0[r], 0.f)) * rv[0][r]);
        e1[r] = (short)f2bf(fexp2(fmaxf(d1[r], 0.f)) * rv[1][r]);
      }
      *(bf16x4*)&Ew[p ^ 1][rowm][q * 4] = e0;
      *(bf16x4*)&Ew[p ^ 1][rowm][16 + q * 4] = e1;
      f32x4 d2 = __builtin_amdgcn_mfma_f32_16x16x32_bf16(atn[2], bg, z4, 0, 0, 0);
      f32x4 d3 = __builtin_amdgcn_mfma_f32_16x16x32_bf16(atn[3], bg, z4, 0, 0, 0);
      bf16x4 e2, e3;
#pragma unroll
      for (int r = 0; r < 4; ++r) {
        e2[r] = (short)f2bf(fexp2(fmaxf(d2[r], 0.f)) * rv[2][r]);
        e3[r] = (short)f2bf(fexp2(fmaxf(d3[r], 0.f)) * rv[3][r]);
      }
      *(bf16x4*)&Ew[p ^ 1][rowm][32 + q * 4] = e2;
      *(bf16x4*)&Ew[p ^ 1][rowm][48 + q * 4] = e3;
    }

    // half-1 E operands + acc (k-step 1: n 32..63)
#pragma unroll
    for (int ms = 0; ms < 4; ++ms)
      efr[ms] = *(const bf16x8*)&Ew[p][ms * 16 + i16][32 + q * 8];
    __builtin_amdgcn_s_setprio(1);
#pragma unroll
    for (int c = 0; c < 3; ++c)
#pragma unroll
      for (int ms = 0; ms < 4; ++ms)
        acc[c][ms] = __builtin_amdgcn_mfma_f32_16x16x32_bf16(yfr1[c], efr[ms], acc[c][ms], 0, 0, 0);
    __builtin_amdgcn_s_setprio(0);

    RAWBAR();  // buf p reads done; buf p^1 writes visible (lgkmcnt only)
  }

  // epilogue: lane holds col = (w*3+c)*16 + q*4 + r, m = mb + ms*16 + i16
  unsigned short* pp = part + (size_t)blockIdx.y * 192 * NN;
#pragma unroll
  for (int c = 0; c < 3; ++c)
#pragma unroll
    for (int ms = 0; ms < 4; ++ms) {
      const int colbase = (w * 3 + c) * 16 + q * 4;
      const int m = mb + ms * 16 + i16;
#pragma unroll
      for (int r = 0; r < 4; ++r)
        pp[(size_t)(colbase + r) * NN + m] = f2bf(acc[c][ms][r]);
    }
}

// ---- reduce NSPLIT bf16 partials + transpose to out[bc][m][t] (pad 12->13) ----
__global__ __launch_bounds__(256) void k_reduce(const unsigned short* __restrict__ part,
                                                float* __restrict__ out) {
  __shared__ float os[3328];  // 256 * 13
  const int tid = threadIdx.x;
  const int m0 = blockIdx.x * 256;
  const int bc = blockIdx.y;
#pragma unroll
  for (int t = 0; t < 12; ++t) {
    const int col = bc * TT + t;
    float s = 0.f;
#pragma unroll
    for (int nc = 0; nc < NSPLIT; ++nc) {
      const unsigned int u = part[((size_t)nc * 192 + col) * NN + m0 + tid];
      s += __uint_as_float(u << 16);
    }
    os[tid * 13 + t] = s;
  }
  __syncthreads();
  float* op = out + (size_t)bc * NN * TT + (size_t)m0 * TT;
#pragma unroll
  for (int j = 0; j < 12; ++j) {
    const int idx = j * 256 + tid;
    op[idx] = os[(idx / 12) * 13 + idx % 12];
  }
}

extern "C" void kernel_launch(void* const* d_in, const int* in_sizes, int n_in,
                              void* d_out, int out_size, void* d_ws, size_t ws_size,
                              hipStream_t stream) {
  const float* x = (const float*)d_in[0];
  const float* nv1 = (const float*)d_in[1];
  const float* nv2 = (const float*)d_in[2];
  const float* tv = (const float*)d_in[3];
  const float* kk = (const float*)d_in[4];
  const int* tind = (const int*)d_in[5];
  float* out = (float*)d_out;

  char* ws = (char*)d_ws;
  unsigned short* t1b  = (unsigned short*)(ws);            //  524288 B
  unsigned short* nv2b = (unsigned short*)(ws + 524288);   //  524288 B
  float* sumsp         = (float*)(ws + 1048576);           //  262144 B (8 x 8192 f32)
  unsigned short* yT   = (unsigned short*)(ws + 1310720);  // 3145728 B -> 4456448
  unsigned short* part = (unsigned short*)(ws + 4456448);  // 25165824 B (bf16)

  k_pre<<<512, 256, 0, stream>>>(x, nv1, nv2, tv, kk, tind, t1b, nv2b, yT);
  k_stats<<<dim3(128, NSPLIT), 256, 0, stream>>>(t1b, nv2b, sumsp);
  k_mega<<<dim3(128, NSPLIT), 256, 0, stream>>>(t1b, nv2b, yT, sumsp, part);
  k_reduce<<<dim3(32, 16), 256, 0, stream>>>(part, out);
}

// Round 12
// 182.121 us; speedup vs baseline: 1.1017x; 1.1017x over previous
//
#include <hip/hip_runtime.h>
#include <hip/hip_bf16.h>

// GDGCN: out[b,c,m,t] = sum_n softmax_row(relu(t1 nv2^T))[n,m] * x[b,c,n,t]
// t1 = nv1 @ (sum_d tv[d] k[d,:,:]);  N=8192, D=32, cols = B*C*T = 192.
// R23: R22's 4-kernel pipeline (non-mega time 101->93us, keep) with the
// k_mega VGPR spill fixed (R22: rv[4] live across acc -> 60MB scratch
// writes, WRITE_SIZE 24.6->85.4MB, dur 71->107us).
//  1) normalization as log2-bias via gen-MFMA C-in: table stores
//     l2r[n] = -log2(sum); E' = exp2(max(logit+l2r, l2r)) (relu+bias in
//     one fmax, no multiplies, C-in replaces z4 for free).
//  2) pack e0/e1 moved before acc k0: d0,d1,l2r0,l2r1 die before the
//     12-MFMA block; live-across-acc ~4 VGPR (< R21). l2r ds_reads at
//     point of use.
// Proven invariants: col-split waves + LDS-E dbuf (R15/16/17 m-splits all
// lost), RAWBAR lgkmcnt-only, ESTR 70, bf16 part, RNE f2bf pack only
// (v_cvt_pk_bf16_f32 NOT RNE on gfx950, R14).

#define NN 8192
#define DD 32
#define TT 12
#define NSPLIT 8
#define CHUNK 1024
#define ESTR 70  // LDS row stride (ushort)

typedef __attribute__((ext_vector_type(8))) short bf16x8;
typedef __attribute__((ext_vector_type(4))) short bf16x4;
typedef __attribute__((ext_vector_type(4))) float f32x4;

static __device__ __forceinline__ unsigned short f2bf(float f) {
  unsigned int u = __float_as_uint(f);
  u = (u + 0x7FFFu + ((u >> 16) & 1u)) >> 16;  // RNE bf16
  return (unsigned short)u;
}

static __device__ __forceinline__ float fexp2(float x) {
#if __has_builtin(__builtin_amdgcn_exp2f)
  return __builtin_amdgcn_exp2f(x);
#else
  return __builtin_exp2f(x);
#endif
}

static __device__ __forceinline__ float flog2(float x) {
#if __has_builtin(__builtin_amdgcn_logf)
  return __builtin_amdgcn_logf(x);
#else
  return __log2f(x);
#endif
}

// Raw barrier: LDS-visibility only (lgkmcnt). Global loads stay in flight.
#define RAWBAR()                                          \
  do {                                                    \
    asm volatile("s_waitcnt lgkmcnt(0)" ::: "memory");    \
    __builtin_amdgcn_sched_barrier(0);                    \
    __builtin_amdgcn_s_barrier();                         \
  } while (0)

// ---- k_pre: core = tv.k ; t1 rows ; nv2 -> bf16 ; yT = bf16(x) transpose ----
// 512 blocks: block b = (bc = b>>5, xb = b&31).
__global__ __launch_bounds__(256) void k_pre(const float* __restrict__ x,
                                             const float* __restrict__ nv1,
                                             const float* __restrict__ nv2,
                                             const float* __restrict__ timevec,
                                             const float* __restrict__ kk,
                                             const int* __restrict__ tind,
                                             unsigned short* __restrict__ t1b,
                                             unsigned short* __restrict__ nv2b,
                                             unsigned short* __restrict__ yT) {
  __shared__ float cs[1024];
  __shared__ float xs[3328];  // 256 * 13 (pad kills stride-12 conflicts)
  const int tid = threadIdx.x;
  const int bid = blockIdx.x;
  const int bc = bid >> 5, xb = bid & 31;
  const int n0 = xb * 256;

  const float* tv = timevec + (size_t)tind[0] * DD;
  for (int idx = tid; idx < 1024; idx += 256) {
    float acc = 0.f;
#pragma unroll
    for (int d = 0; d < DD; ++d) acc += tv[d] * kk[d * 1024 + idx];
    cs[idx] = acc;
  }
  const float* xp = x + (size_t)bc * NN * TT + (size_t)n0 * TT;
#pragma unroll
  for (int j = 0; j < 12; ++j) {
    const int idx = j * 256 + tid;
    xs[(idx / 12) * 13 + idx % 12] = xp[idx];
  }
  __syncthreads();

  const int f = tid & 31, sub = tid >> 5;
  const int tb = bid * 16;
#pragma unroll
  for (int it = 0; it < 2; ++it) {
    const int n = tb + it * 8 + sub;
    const float* nr = nv1 + (size_t)n * DD;
    float acc = 0.f;
#pragma unroll
    for (int e = 0; e < DD; ++e) acc += nr[e] * cs[e * DD + f];
    t1b[(size_t)n * DD + f] = f2bf(acc * 1.4426950408889634f);  // fold log2(e)
  }
#pragma unroll
  for (int it = 0; it < 2; ++it) {
    const int idx = bid * 512 + it * 256 + tid;
    nv2b[idx] = f2bf(nv2[idx]);
  }
#pragma unroll
  for (int t = 0; t < 12; ++t)
    yT[(size_t)(bc * TT + t) * NN + n0 + tid] = f2bf(xs[tid * 13 + t]);
}

// ---- sums_part[j][n] = sum_{m in chunk j} exp2(relu(t1[n].nv2[m])) ----
// grid (128 n, 8 m-chunks of 1024); no atomics, no init, deterministic.
__global__ __launch_bounds__(256) void k_stats(const unsigned short* __restrict__ t1b,
                                               const unsigned short* __restrict__ nv2b,
                                               float* __restrict__ sumsp) {
  const int tid = threadIdx.x;
  const int w = tid >> 6, lane = tid & 63, q = lane >> 4, i16 = lane & 15;
  const int nbase = blockIdx.x * 64 + w * 16;
  bf16x8 a = *(const bf16x8*)(t1b + (size_t)(nbase + i16) * DD + q * 8);
  const f32x4 z4 = {0.f, 0.f, 0.f, 0.f};
  float s[4] = {0.f, 0.f, 0.f, 0.f};
  const int m0 = blockIdx.y * 1024;
#define LDB(mt, u) (*(const bf16x8*)(nv2b + (size_t)((mt) + (u)*16 + i16) * DD + q * 8))
  bf16x8 b0 = LDB(m0, 0), b1 = LDB(m0, 1), b2 = LDB(m0, 2), b3 = LDB(m0, 3);
  for (int mt = m0; mt < m0 + 1024; mt += 64) {
    const int mtn = (mt + 64 < m0 + 1024) ? (mt + 64) : mt;  // clamp: dummy reload
    bf16x8 n0 = LDB(mtn, 0), n1 = LDB(mtn, 1), n2 = LDB(mtn, 2), n3 = LDB(mtn, 3);
    f32x4 d;
    d = __builtin_amdgcn_mfma_f32_16x16x32_bf16(a, b0, z4, 0, 0, 0);
#pragma unroll
    for (int r = 0; r < 4; ++r) s[r] += fexp2(fmaxf(d[r], 0.f));
    d = __builtin_amdgcn_mfma_f32_16x16x32_bf16(a, b1, z4, 0, 0, 0);
#pragma unroll
    for (int r = 0; r < 4; ++r) s[r] += fexp2(fmaxf(d[r], 0.f));
    d = __builtin_amdgcn_mfma_f32_16x16x32_bf16(a, b2, z4, 0, 0, 0);
#pragma unroll
    for (int r = 0; r < 4; ++r) s[r] += fexp2(fmaxf(d[r], 0.f));
    d = __builtin_amdgcn_mfma_f32_16x16x32_bf16(a, b3, z4, 0, 0, 0);
#pragma unroll
    for (int r = 0; r < 4; ++r) s[r] += fexp2(fmaxf(d[r], 0.f));
    b0 = n0; b1 = n1; b2 = n2; b3 = n3;
  }
#undef LDB
#pragma unroll
  for (int r = 0; r < 4; ++r)
    for (int off = 1; off < 16; off <<= 1) s[r] += __shfl_xor(s[r], off, 64);
  if (i16 == 0) {
#pragma unroll
    for (int r = 0; r < 4; ++r)
      sumsp[(size_t)blockIdx.y * NN + nbase + q * 4 + r] = s[r];
  }
}

// ---- k_mega: part[nc][col][m] = sum_{n in chunk} E'[n][m] * y[col][n] ----
// E' = exp2(max(logit + l2r[n], l2r[n])), l2r = -log2(sum): softmax
// normalization + relu folded into the gen MFMA C-in and one fmax.
__global__ __launch_bounds__(256, 4) void k_mega(const unsigned short* __restrict__ t1b,
                                                 const unsigned short* __restrict__ nv2b,
                                                 const unsigned short* __restrict__ yT,
                                                 const float* __restrict__ sumsp,
                                                 unsigned short* __restrict__ part) {
  const int tid = threadIdx.x;
  const int w = tid >> 6, lane = tid & 63, q = lane >> 4, i16 = lane & 15;
  const int mb = blockIdx.x * 64;
  const int nt0 = blockIdx.y * CHUNK;

  __shared__ unsigned short Ew[2][64][ESTR];  // 17920 B
  __shared__ f32x4 bias_v[256];               //  4096 B: l2r[1024 n]

  // prologue A: l2r table (deterministic j-order sum, then -log2)
  {
    float* bl = (float*)bias_v;
    for (int k = tid; k < 1024; k += 256) {
      float ssum = 0.f;
#pragma unroll
      for (int j = 0; j < NSPLIT; ++j) ssum += sumsp[(size_t)j * NN + nt0 + k];
      bl[k] = -flog2(ssum);
    }
  }

  // gen B-frag (loop-invariant): B[d][m=i16] = nv2[mb + w*16 + i16][d]
  const bf16x8 bg = *(const bf16x8*)(nv2b + (size_t)(mb + w * 16 + i16) * DD + q * 8);
  const int rowm = w * 16 + i16;

  f32x4 acc[3][4];
#pragma unroll
  for (int c = 0; c < 3; ++c)
#pragma unroll
    for (int ms = 0; ms < 4; ++ms) acc[c][ms] = (f32x4){0.f, 0.f, 0.f, 0.f};

  RAWBAR();  // bias table visible

  // prologue B: generate stage 0 (64 n) into buf 0 (C-in bias + fmax relu)
#pragma unroll
  for (int s = 0; s < 4; ++s) {
    bf16x8 at = *(const bf16x8*)(t1b + (size_t)(nt0 + s * 16 + i16) * DD + q * 8);
    const f32x4 bv = bias_v[s * 4 + q];  // l2r[n = s*16 + q*4 + r]
    f32x4 d = __builtin_amdgcn_mfma_f32_16x16x32_bf16(at, bg, bv, 0, 0, 0);
    bf16x4 e;
#pragma unroll
    for (int r = 0; r < 4; ++r) e[r] = (short)f2bf(fexp2(fmaxf(d[r], bv[r])));
    *(bf16x4*)&Ew[0][rowm][s * 16 + q * 4] = e;
  }
  RAWBAR();

  int p = 0;
  for (int st = 0; st < 16; ++st, p ^= 1) {
    const int nt = nt0 + st * 64;
    const bool more = (st < 15);

    // --- stage top: issue ALL global loads (y both halves, next t1) ---
    bf16x8 yfr0[3], yfr1[3];
#pragma unroll
    for (int c = 0; c < 3; ++c) {
      const unsigned short* ybase = yT + (size_t)((w * 3 + c) * 16 + i16) * NN + nt + q * 8;
      yfr0[c] = *(const bf16x8*)ybase;
      yfr1[c] = *(const bf16x8*)(ybase + 32);
    }
    bf16x8 atn[4];
    if (more) {
#pragma unroll
      for (int s = 0; s < 4; ++s)
        atn[s] = *(const bf16x8*)(t1b + (size_t)(nt + 64 + s * 16 + i16) * DD + q * 8);
    }

    // half-0 E operands
    bf16x8 efr[4];
#pragma unroll
    for (int ms = 0; ms < 4; ++ms)
      efr[ms] = *(const bf16x8*)&Ew[p][ms * 16 + i16][q * 8];

    // gen + pack s0,s1 for stage st+1 (before acc: d/bv die here -> no
    // VGPRs carried across the 12-MFMA block; fixes R22's spill)
    if (more) {
      const f32x4 bv0 = bias_v[(st + 1) * 16 + q];
      const f32x4 bv1 = bias_v[(st + 1) * 16 + 4 + q];
      f32x4 d0 = __builtin_amdgcn_mfma_f32_16x16x32_bf16(atn[0], bg, bv0, 0, 0, 0);
      f32x4 d1 = __builtin_amdgcn_mfma_f32_16x16x32_bf16(atn[1], bg, bv1, 0, 0, 0);
      bf16x4 e0, e1;
#pragma unroll
      for (int r = 0; r < 4; ++r) {
        e0[r] = (short)f2bf(fexp2(fmaxf(d0[r], bv0[r])));
        e1[r] = (short)f2bf(fexp2(fmaxf(d1[r], bv1[r])));
      }
      *(bf16x4*)&Ew[p ^ 1][rowm][q * 4] = e0;
      *(bf16x4*)&Ew[p ^ 1][rowm][16 + q * 4] = e1;
    }

    // acc k-step 0 (12 MFMAs), priority-boosted (T5)
    __builtin_amdgcn_s_setprio(1);
#pragma unroll
    for (int c = 0; c < 3; ++c)
#pragma unroll
      for (int ms = 0; ms < 4; ++ms)
        acc[c][ms] = __builtin_amdgcn_mfma_f32_16x16x32_bf16(yfr0[c], efr[ms], acc[c][ms], 0, 0, 0);
    __builtin_amdgcn_s_setprio(0);

    // gen + pack s2,s3 for stage st+1
    if (more) {
      const f32x4 bv2 = bias_v[(st + 1) * 16 + 8 + q];
      const f32x4 bv3 = bias_v[(st + 1) * 16 + 12 + q];
      f32x4 d2 = __builtin_amdgcn_mfma_f32_16x16x32_bf16(atn[2], bg, bv2, 0, 0, 0);
      f32x4 d3 = __builtin_amdgcn_mfma_f32_16x16x32_bf16(atn[3], bg, bv3, 0, 0, 0);
      bf16x4 e2, e3;
#pragma unroll
      for (int r = 0; r < 4; ++r) {
        e2[r] = (short)f2bf(fexp2(fmaxf(d2[r], bv2[r])));
        e3[r] = (short)f2bf(fexp2(fmaxf(d3[r], bv3[r])));
      }
      *(bf16x4*)&Ew[p ^ 1][rowm][32 + q * 4] = e2;
      *(bf16x4*)&Ew[p ^ 1][rowm][48 + q * 4] = e3;
    }

    // half-1 E operands + acc (k-step 1: n 32..63)
#pragma unroll
    for (int ms = 0; ms < 4; ++ms)
      efr[ms] = *(const bf16x8*)&Ew[p][ms * 16 + i16][32 + q * 8];
    __builtin_amdgcn_s_setprio(1);
#pragma unroll
    for (int c = 0; c < 3; ++c)
#pragma unroll
      for (int ms = 0; ms < 4; ++ms)
        acc[c][ms] = __builtin_amdgcn_mfma_f32_16x16x32_bf16(yfr1[c], efr[ms], acc[c][ms], 0, 0, 0);
    __builtin_amdgcn_s_setprio(0);

    RAWBAR();  // buf p reads done; buf p^1 writes visible (lgkmcnt only)
  }

  // epilogue: lane holds col = (w*3+c)*16 + q*4 + r, m = mb + ms*16 + i16
  unsigned short* pp = part + (size_t)blockIdx.y * 192 * NN;
#pragma unroll
  for (int c = 0; c < 3; ++c)
#pragma unroll
    for (int ms = 0; ms < 4; ++ms) {
      const int colbase = (w * 3 + c) * 16 + q * 4;
      const int m = mb + ms * 16 + i16;
#pragma unroll
      for (int r = 0; r < 4; ++r)
        pp[(size_t)(colbase + r) * NN + m] = f2bf(acc[c][ms][r]);
    }
}

// ---- reduce NSPLIT bf16 partials + transpose to out[bc][m][t] (pad 12->13) ----
__global__ __launch_bounds__(256) void k_reduce(const unsigned short* __restrict__ part,
                                                float* __restrict__ out) {
  __shared__ float os[3328];  // 256 * 13
  const int tid = threadIdx.x;
  const int m0 = blockIdx.x * 256;
  const int bc = blockIdx.y;
#pragma unroll
  for (int t = 0; t < 12; ++t) {
    const int col = bc * TT + t;
    float s = 0.f;
#pragma unroll
    for (int nc = 0; nc < NSPLIT; ++nc) {
      const unsigned int u = part[((size_t)nc * 192 + col) * NN + m0 + tid];
      s += __uint_as_float(u << 16);
    }
    os[tid * 13 + t] = s;
  }
  __syncthreads();
  float* op = out + (size_t)bc * NN * TT + (size_t)m0 * TT;
#pragma unroll
  for (int j = 0; j < 12; ++j) {
    const int idx = j * 256 + tid;
    op[idx] = os[(idx / 12) * 13 + idx % 12];
  }
}

extern "C" void kernel_launch(void* const* d_in, const int* in_sizes, int n_in,
                              void* d_out, int out_size, void* d_ws, size_t ws_size,
                              hipStream_t stream) {
  const float* x = (const float*)d_in[0];
  const float* nv1 = (const float*)d_in[1];
  const float* nv2 = (const float*)d_in[2];
  const float* tv = (const float*)d_in[3];
  const float* kk = (const float*)d_in[4];
  const int* tind = (const int*)d_in[5];
  float* out = (float*)d_out;

  char* ws = (char*)d_ws;
  unsigned short* t1b  = (unsigned short*)(ws);            //  524288 B
  unsigned short* nv2b = (unsigned short*)(ws + 524288);   //  524288 B
  float* sumsp         = (float*)(ws + 1048576);           //  262144 B (8 x 8192 f32)
  unsigned short* yT   = (unsigned short*)(ws + 1310720);  // 3145728 B -> 4456448
  unsigned short* part = (unsigned short*)(ws + 4456448);  // 25165824 B (bf16)

  k_pre<<<512, 256, 0, stream>>>(x, nv1, nv2, tv, kk, tind, t1b, nv2b, yT);
  k_stats<<<dim3(128, NSPLIT), 256, 0, stream>>>(t1b, nv2b, sumsp);
  k_mega<<<dim3(128, NSPLIT), 256, 0, stream>>>(t1b, nv2b, yT, sumsp, part);
  k_reduce<<<dim3(32, 16), 256, 0, stream>>>(part, out);
}